// Round 8
// baseline (928.116 us; speedup 1.0000x reference)
//
#include <hip/hip_runtime.h>
#include <hip/hip_bf16.h>
#include <hip/hip_cooperative_groups.h>

namespace cg = cooperative_groups;

#define B_ 8
#define S_ 128
#define H_ 512
#define E_ 512
#define NST 8
#define R_ 1024
#define N2 2048
#define KD 512
#define LDA 72          // LDS row pitch in shorts (fragment ds_read_b128: 2-way = free)
#define NBLK 256
#define NTHR 512
#define GS (NBLK*NTHR)  // 131072 threads grid-wide

typedef __hip_bfloat16 bf16;
typedef __attribute__((ext_vector_type(8))) short v8s;
typedef __attribute__((ext_vector_type(4))) float v4f;

struct Params {
  const int* ids; const int* tree;
  const void* emb; const void* Wioux; const void* Wr; const void* br;
  const void* Wl;  const void* bl;    const void* Wfx;
  const void* W0;  const void* b0;    const void* W1; const void* b1;
  const void* W2;  const void* b2;    const void* W3; const void* b3;
  float* XO; float* T; float* h0; float* c0; float* h1; float* c1; float* bcat;
  unsigned short* WxT; unsigned short* WcatT; unsigned short* xb; unsigned short* hb;
  int* msk; int* rnk; int* cnt; int* off; int* cur; int* ent; int* flags;
  float* out;
};

__device__ __forceinline__ float sigm(float x){ return 1.0f/(1.0f + expf(-x)); }
__device__ __forceinline__ float load_in(const void* p, long long i, int isb){
    return isb ? __bfloat162float(((const bf16*)p)[i]) : ((const float*)p)[i];
}
__device__ __forceinline__ int idx_read(const int* p, int j, int is64){
    return is64 ? p[2*j] : p[j];
}
__device__ __forceinline__ unsigned short f2b(float v){
    bf16 b = __float2bfloat16(v);
    return *(unsigned short*)&b;
}

// ---- GEMM tile phase: C[1024][2048] = A[1024][512]bf16 @ BT[2048][512]^T (+bias) ----
// 256 tiles of 64x128; 8 waves (2m x 4n) of 32x32; register-prefetched staging (r7-proven).
__device__ __forceinline__ void gemm_tile(const unsigned short* __restrict__ A,
                                          const unsigned short* __restrict__ BT,
                                          const float* __restrict__ bias,
                                          float* __restrict__ C,
                                          int bid, int tid, short* As, short* Bs){
    int bm = bid >> 4, bn = bid & 15;
    int lane = tid & 63, wave = tid >> 6;
    int wm = wave & 1, wn = wave >> 1;          // 2 x 4 wave grid
    int lm = lane & 15, quad = lane >> 4;
    v4f acc[2][2];
    #pragma unroll
    for (int i=0;i<2;++i)
        #pragma unroll
        for (int j=0;j<2;++j) acc[i][j] = (v4f)0.0f;

    int srow = tid >> 3, sg = (tid & 7)*8;      // A: 64 rows (1 v8s/thr); B: 2x64 rows
    const unsigned short* Ab = A  + (size_t)(bm*64)*KD;
    const unsigned short* Bb = BT + (size_t)(bn*128)*KD;
    v8s pa, pb0, pb1;
    pa  = *(const v8s*)(Ab + (size_t)srow*KD + sg);
    pb0 = *(const v8s*)(Bb + (size_t)srow*KD + sg);
    pb1 = *(const v8s*)(Bb + (size_t)(64+srow)*KD + sg);
    for (int k0 = 0; k0 < KD; k0 += 64){
        __syncthreads();                        // prior readers done
        *(v8s*)&As[srow*LDA + sg] = pa;
        *(v8s*)&Bs[srow*LDA + sg] = pb0;
        *(v8s*)&Bs[(64+srow)*LDA + sg] = pb1;
        __syncthreads();
        int k1 = k0 + 64;
        if (k1 < KD){                           // prefetch overlaps MFMA phase
            pa  = *(const v8s*)(Ab + (size_t)srow*KD + k1 + sg);
            pb0 = *(const v8s*)(Bb + (size_t)srow*KD + k1 + sg);
            pb1 = *(const v8s*)(Bb + (size_t)(64+srow)*KD + k1 + sg);
        }
        #pragma unroll
        for (int kk = 0; kk < 64; kk += 32){
            v8s af[2], bf[2];
            #pragma unroll
            for (int i=0;i<2;++i){
                af[i] = *(const v8s*)&As[(wm*32 + i*16 + lm)*LDA + kk + quad*8];
                bf[i] = *(const v8s*)&Bs[(wn*32 + i*16 + lm)*LDA + kk + quad*8];
            }
            #pragma unroll
            for (int i=0;i<2;++i)
                #pragma unroll
                for (int j=0;j<2;++j)
                    acc[i][j] = __builtin_amdgcn_mfma_f32_16x16x32_bf16(af[i], bf[j], acc[i][j], 0, 0, 0);
        }
    }
    #pragma unroll
    for (int j=0;j<2;++j){
        int n = bn*128 + wn*32 + j*16 + lm;
        float bv = bias ? bias[n] : 0.0f;
        #pragma unroll
        for (int i=0;i<2;++i){
            int m0 = bm*64 + wm*32 + i*16 + quad*4;
            #pragma unroll
            for (int rg = 0; rg < 4; ++rg)
                C[(size_t)(m0+rg)*N2 + n] = acc[i][j][rg] + bv;
        }
    }
}

__global__ __launch_bounds__(NTHR, 2) void mega(Params p){
    cg::grid_group gg = cg::this_grid();
    int bid = blockIdx.x, tid = threadIdx.x;
    __shared__ short As[64*LDA];
    __shared__ short Bs[128*LDA];
    __shared__ int aux[NTHR];
    __shared__ int wt[8];

    // ---------- P0: dtype probes ----------
    if (bid < 17){
        const void* ts[15] = {p.emb,p.Wioux,p.Wr,p.br,p.Wl,p.bl,p.Wfx,
                              p.W0,p.b0,p.W1,p.b1,p.W2,p.b2,p.W3,p.b3};
        int bad = 0;
        if (bid < 15){
            unsigned short u = ((const unsigned short*)ts[bid])[tid];
            bad = (((u >> 7) & 0xFF) >= 140);
        } else {
            const int* q = (bid == 15) ? p.ids : p.tree;
            int n = (bid == 15) ? 1024 : 2048;
            for (int j = tid; j < n; j += NTHR) if (j & 1) bad |= (q[j] != 0);
        }
        unsigned long long bl_ = __ballot(bad);
        if ((tid & 63) == 0) wt[tid >> 6] = (bl_ != 0ull) ? 1 : 0;
        __syncthreads();
        if (tid == 0){
            int any = 0;
            for (int w = 0; w < 8; ++w) any |= wt[w];
            p.flags[(bid < 15) ? bid : (16 + bid - 15)] = any ? 0 : 1;
        }
    }
    gg.sync();

    int is64 = p.flags[17];

    // ---------- P1: rank+count (bid<8) + packs + zero-init (all blocks) ----------
    if (bid < 8){
        int st = bid;
        for (int c = tid; c < R_; c += NTHR){
            p.cnt[(0*NST + st)*R_ + c] = 0;
            p.cnt[(1*NST + st)*R_ + c] = 0;
            p.cnt[(2*NST + st)*R_ + c] = 0;
        }
        __syncthreads();
        int runbase = 0;
        for (int ch = 0; ch < 2; ++ch){
            int t = ch*NTHR + tid;
            int b = t >> 7, s = t & 127;
            int base = (b*NST + st)*3*S_;
            int d0 = idx_read(p.tree, base + s, is64);
            int rd = (b<<7) + d0;
            int rr = (b<<7) + idx_read(p.tree, base + S_ + s, is64);
            int rl = (b<<7) + idx_read(p.tree, base + 2*S_ + s, is64);
            int m = (d0 != 0) ? 1 : 0;
            unsigned long long bal = __ballot(m);
            int lane = tid & 63, wv = tid >> 6;
            if (lane == 0) wt[wv] = __popcll(bal);
            __syncthreads();
            int bp = runbase, tot = 0;
            for (int w = 0; w < wv; ++w) bp += wt[w];
            for (int w = 0; w < 8; ++w) tot += wt[w];
            int rank = bp + __popcll(bal & ((1ull << lane) - 1ull));
            p.msk[st*R_ + t] = m;
            p.rnk[st*R_ + t] = m ? rank : 0;
            atomicAdd(&p.cnt[(0*NST + st)*R_ + rr], 1);
            atomicAdd(&p.cnt[(1*NST + st)*R_ + rl], 1);
            atomicAdd(&p.cnt[(2*NST + st)*R_ + rd], 1);
            runbase += tot;
            __syncthreads();
        }
    }
    {
        int gt = bid*NTHR + tid;
        int f_wx = p.flags[1], f_wf = p.flags[6];
        for (int u = gt; u < 131072; u += GS){          // WxT: 2048 n x 64 kgroups
            int n = u >> 6, k0 = (u & 63)*8;
            unsigned short tmp[8];
            #pragma unroll
            for (int i = 0; i < 8; ++i){
                float v = (n < 1536) ? load_in(p.Wioux, (long long)(k0+i)*1536 + n, f_wx)
                                     : load_in(p.Wfx,   (long long)(k0+i)*512 + (n-1536), f_wf);
                tmp[i] = f2b(v);
            }
            *(v8s*)&p.WxT[(size_t)n*KD + k0] = *(v8s*)tmp;
        }
        int fWr=p.flags[2], fWl=p.flags[4], fW0=p.flags[7], fW1=p.flags[9], fW2=p.flags[11], fW3=p.flags[13];
        for (int u = gt; u < 131072; u += GS){          // WcatT
            int n = u >> 6, k0 = (u & 63)*8;
            unsigned short tmp[8];
            #pragma unroll
            for (int i = 0; i < 8; ++i){
                long long k = k0 + i;
                float v;
                if      (n <  512) v = load_in(p.Wr, k*1536 + n, fWr);
                else if (n < 1024) v = load_in(p.Wl, k*1536 + (n-512), fWl);
                else if (n < 1536) { int c = n-1024; v = load_in(p.W0, k*512+c, fW0) + load_in(p.W1, k*512+c, fW1); }
                else               { int c = n-1536; v = load_in(p.W2, k*512+c, fW2) + load_in(p.W3, k*512+c, fW3); }
                tmp[i] = f2b(v);
            }
            *(v8s*)&p.WcatT[(size_t)n*KD + k0] = *(v8s*)tmp;
        }
        int fbr=p.flags[3], fbl=p.flags[5], fb0=p.flags[8], fb1=p.flags[10], fb2=p.flags[12], fb3=p.flags[14];
        for (int n = gt; n < 2048; n += GS){            // bcat
            float v;
            if      (n <  512) v = load_in(p.br, n, fbr);
            else if (n < 1024) v = load_in(p.bl, n-512, fbl);
            else if (n < 1536) v = load_in(p.b0, n-1024, fb0) + load_in(p.b1, n-1024, fb1);
            else               v = load_in(p.b2, n-1536, fb2) + load_in(p.b3, n-1536, fb3);
            p.bcat[n] = v;
        }
        int f_emb = p.flags[0], i64i = p.flags[16];
        for (int u = gt; u < 65536; u += GS){           // xb: 1024 rows x 64 groups
            int r = u >> 6, c0 = (u & 63)*8;
            long long base = (long long)idx_read(p.ids, r, i64i)*E_ + c0;
            unsigned short tmp[8];
            #pragma unroll
            for (int i = 0; i < 8; ++i) tmp[i] = f2b(load_in(p.emb, base + i, f_emb));
            *(v8s*)&p.xb[(size_t)r*KD + c0] = *(v8s*)tmp;
        }
        for (int u = gt; u < 262144; u += GS)           // zero h0+c0 (contiguous 4 MB)
            ((float4*)p.h0)[u] = make_float4(0.f,0.f,0.f,0.f);
        for (int u = gt; u < 65536; u += GS)            // zero hb (1 MB)
            ((float4*)p.hb)[u] = make_float4(0.f,0.f,0.f,0.f);
    }
    gg.sync();

    // ---------- P2: CSR scans (bid<24) + XO GEMM (all) ----------
    if (bid < 24){
        int a = bid >> 3, st = bid & 7;
        int base = (a*NST + st)*R_;
        int v0 = p.cnt[base + tid*2], v1 = p.cnt[base + tid*2 + 1];
        int tot = v0 + v1;
        aux[tid] = tot;
        __syncthreads();
        for (int d = 1; d < NTHR; d <<= 1){
            int x = (tid >= d) ? aux[tid - d] : 0;
            __syncthreads();
            aux[tid] += x;
            __syncthreads();
        }
        int excl = aux[tid] - tot;
        p.off[base + tid*2]     = excl;      p.cur[base + tid*2]     = excl;
        p.off[base + tid*2 + 1] = excl + v0; p.cur[base + tid*2 + 1] = excl + v0;
    }
    gemm_tile(p.xb, p.WxT, (const float*)0, p.XO, bid, tid, As, Bs);
    gg.sync();

    // ---------- P3: CSR fill (bid<8) + step-0 GEMM (all) ----------
    if (bid < 8){
        int st = bid;
        for (int ch = 0; ch < 2; ++ch){
            int t = ch*NTHR + tid;
            int b = t >> 7, s = t & 127;
            int base = (b*NST + st)*3*S_;
            int rd = (b<<7) + idx_read(p.tree, base + s, is64);
            int rr = (b<<7) + idx_read(p.tree, base + S_ + s, is64);
            int rl = (b<<7) + idx_read(p.tree, base + 2*S_ + s, is64);
            int p0 = atomicAdd(&p.cur[(0*NST + st)*R_ + rr], 1);
            p.ent[(0*NST + st)*R_ + p0] = t;
            int p1 = atomicAdd(&p.cur[(1*NST + st)*R_ + rl], 1);
            p.ent[(1*NST + st)*R_ + p1] = t;
            int p2 = atomicAdd(&p.cur[(2*NST + st)*R_ + rd], 1);
            p.ent[(2*NST + st)*R_ + p2] = t | (rr << 10) | (rl << 20);
        }
    }
    gemm_tile(p.hb, p.WcatT, p.bcat, p.T, bid, tid, As, Bs);
    gg.sync();

    // ---------- step loop ----------
    float *hc = p.h0, *cc = p.c0, *hn = p.h1, *cn = p.c1;
    for (int st = 0; st < NST; ++st){
        // epilogue: 4 rows per block, c = tid (512 == H_)
        for (int q = 0; q < 4; ++q){
            int r = bid*4 + q;
            int c = tid;
            if (!p.msk[st*R_ + r]){
                float hv = hc[(size_t)r*H_ + c];
                float cv = cc[(size_t)r*H_ + c];
                hn[(size_t)r*H_ + c] = hv;
                cn[(size_t)r*H_ + c] = cv;
                p.hb[(size_t)r*KD + c] = f2b(hv);
                if (st == NST-1) p.out[(size_t)r*H_ + c] = hv;
            } else {
                int j = p.rnk[st*R_ + r];
                int bR = p.off[(0*NST+st)*R_ + j], dR = p.cnt[(0*NST+st)*R_ + j];
                int bL = p.off[(1*NST+st)*R_ + j], dL = p.cnt[(1*NST+st)*R_ + j];
                int bD = p.off[(2*NST+st)*R_ + j], dD = p.cnt[(2*NST+st)*R_ + j];
                const int* eR = p.ent + (0*NST+st)*R_ + bR;
                const int* eL = p.ent + (1*NST+st)*R_ + bL;
                const int* eD = p.ent + (2*NST+st)*R_ + bD;
                const float* xo = p.XO + (size_t)j*N2;
                float scv = 0.f;
                for (int e = 0; e < dR; ++e) scv += p.T[(size_t)eR[e]*N2 + c];
                for (int e = 0; e < dL; ++e) scv += p.T[(size_t)eL[e]*N2 + 512 + c];
                float fxv = xo[1536 + c];
                float csc = 0.f;
                for (int e = 0; e < dD; ++e){
                    int pk = eD[e];
                    int s  = pk & 1023, rr = (pk >> 10) & 1023, rl = (pk >> 20) & 1023;
                    float f = sigm(fxv + p.T[(size_t)rr*N2 + 1024 + c]
                                       + p.T[(size_t)rl*N2 + 1536 + c]);
                    csc += f * cc[(size_t)s*H_ + c];
                }
                float ig = sigm(xo[c] + scv);
                float og = sigm(xo[512 + c]);
                float ug = tanhf(xo[1024 + c]);
                float cf = ig*ug + csc;
                float hf = og * tanhf(cf);
                hn[(size_t)r*H_ + c] = hf;
                cn[(size_t)r*H_ + c] = cf;
                p.hb[(size_t)r*KD + c] = f2b(hf);
                if (st == NST-1) p.out[(size_t)r*H_ + c] = hf;
            }
        }
        gg.sync();
        if (st < NST-1){
            gemm_tile(p.hb, p.WcatT, p.bcat, p.T, bid, tid, As, Bs);
            gg.sync();
        }
        float* t1 = hc; hc = hn; hn = t1;
        float* t2 = cc; cc = cn; cn = t2;
    }
}

extern "C" void kernel_launch(void* const* d_in, const int* in_sizes, int n_in,
                              void* d_out, int out_size, void* d_ws, size_t ws_size,
                              hipStream_t stream) {
    char* wp = (char*)d_ws;
    auto alloc = [&](size_t bytes) -> void* {
        void* q = (void*)wp;
        wp += (bytes + 255) & ~(size_t)255;
        return q;
    };
    float*          XO     = (float*)alloc((size_t)R_*N2*4);
    float*          T      = (float*)alloc((size_t)R_*N2*4);
    float*          h0     = (float*)alloc((size_t)R_*H_*4);   // contiguous with c0
    float*          c0     = (float*)alloc((size_t)R_*H_*4);
    float*          h1     = (float*)alloc((size_t)R_*H_*4);
    float*          c1     = (float*)alloc((size_t)R_*H_*4);
    unsigned short* WxT    = (unsigned short*)alloc((size_t)N2*KD*2);
    unsigned short* WcatT  = (unsigned short*)alloc((size_t)N2*KD*2);
    float*          bcat   = (float*)alloc((size_t)N2*4);
    unsigned short* xb     = (unsigned short*)alloc((size_t)R_*KD*2);
    unsigned short* hb     = (unsigned short*)alloc((size_t)R_*KD*2);
    int*            msk    = (int*)alloc((size_t)NST*R_*4);
    int*            rnk    = (int*)alloc((size_t)NST*R_*4);
    int*            cnt    = (int*)alloc((size_t)3*NST*R_*4);
    int*            off    = (int*)alloc((size_t)3*NST*R_*4);
    int*            cur    = (int*)alloc((size_t)3*NST*R_*4);
    int*            ent    = (int*)alloc((size_t)3*NST*R_*4);
    int*            flags  = (int*)alloc(256);

    Params prm;
    prm.ids = (const int*)d_in[0];  prm.tree = (const int*)d_in[1];
    prm.emb = d_in[2];  prm.Wioux = d_in[3];
    prm.Wr  = d_in[4];  prm.br = d_in[5];
    prm.Wl  = d_in[6];  prm.bl = d_in[7];
    prm.Wfx = d_in[8];
    prm.W0 = d_in[9];   prm.b0 = d_in[10];
    prm.W1 = d_in[11];  prm.b1 = d_in[12];
    prm.W2 = d_in[13];  prm.b2 = d_in[14];
    prm.W3 = d_in[15];  prm.b3 = d_in[16];
    prm.XO = XO; prm.T = T; prm.h0 = h0; prm.c0 = c0; prm.h1 = h1; prm.c1 = c1;
    prm.bcat = bcat; prm.WxT = WxT; prm.WcatT = WcatT; prm.xb = xb; prm.hb = hb;
    prm.msk = msk; prm.rnk = rnk; prm.cnt = cnt; prm.off = off; prm.cur = cur;
    prm.ent = ent; prm.flags = flags;
    prm.out = (float*)d_out;        // fp32 output (verified r4)

    void* kargs[] = { (void*)&prm };
    hipLaunchCooperativeKernel((const void*)mega, dim3(NBLK), dim3(NTHR),
                               kargs, 0, stream);
}

// Round 9
// 288.558 us; speedup vs baseline: 3.2164x; 3.2164x over previous
//
#include <hip/hip_runtime.h>
#include <hip/hip_bf16.h>

#define B_ 8
#define S_ 128
#define H_ 512
#define E_ 512
#define NST 8
#define R_ 1024
#define N2 2048
#define KD 512
#define LDA 72          // LDS row pitch in shorts (fragment ds_read_b128: 2-way = free)

typedef __hip_bfloat16 bf16;
typedef __attribute__((ext_vector_type(8))) short v8s;
typedef __attribute__((ext_vector_type(4))) float v4f;

__device__ __forceinline__ float sigm(float x){ return 1.0f/(1.0f + expf(-x)); }
__device__ __forceinline__ float load_in(const void* p, long long i, int isb){
    return isb ? __bfloat162float(((const bf16*)p)[i]) : ((const float*)p)[i];
}
__device__ __forceinline__ int idx_read(const int* p, int j, int is64){
    return is64 ? p[2*j] : p[j];
}
__device__ __forceinline__ unsigned short f2b(float v){
    bf16 b = __float2bfloat16(v);
    return *(unsigned short*)&b;
}

// ---- K1: dtype probes (bid 0..14 float tensors, 15/16 int tensors) ----
__global__ void probe_all(const void* t0, const void* t1, const void* t2, const void* t3,
                          const void* t4, const void* t5, const void* t6, const void* t7,
                          const void* t8, const void* t9, const void* t10, const void* t11,
                          const void* t12, const void* t13, const void* t14,
                          const int* __restrict__ ids, const int* __restrict__ tree,
                          int* __restrict__ flags){
    const void* ts[15] = {t0,t1,t2,t3,t4,t5,t6,t7,t8,t9,t10,t11,t12,t13,t14};
    int bid = blockIdx.x, t = threadIdx.x;   // 1024 threads
    int bad = 0;
    if (bid < 15){
        if (t < 512){
            unsigned short u = ((const unsigned short*)ts[bid])[t];
            bad = (((u >> 7) & 0xFF) >= 140);
        }
    } else {
        const int* p = (bid == 15) ? ids : tree;
        int n = (bid == 15) ? 1024 : 2048;
        for (int j = t; j < n; j += 1024)
            if (j & 1) bad |= (p[j] != 0);
    }
    unsigned long long bl = __ballot(bad);
    __shared__ int acc[16];
    if ((t & 63) == 0) acc[t >> 6] = (bl != 0ull) ? 1 : 0;
    __syncthreads();
    if (t == 0){
        int any = 0;
        for (int w = 0; w < 16; ++w) any |= acc[w];
        flags[(bid < 15) ? bid : (16 + bid - 15)] = any ? 0 : 1;
    }
}

// ---- K2: rank+CSR-count (bid<8) + all one-time packs + zero-init (512 thr) ----
#define NB2 320
#define GS2 (NB2*512)
__global__ __launch_bounds__(512)
void rank_pack(const void* __restrict__ Wioux, const void* __restrict__ Wfx,
               const void* __restrict__ Wr, const void* __restrict__ Wl,
               const void* __restrict__ W0, const void* __restrict__ W1,
               const void* __restrict__ W2, const void* __restrict__ W3,
               const void* __restrict__ br, const void* __restrict__ bl,
               const void* __restrict__ b0, const void* __restrict__ b1,
               const void* __restrict__ b2, const void* __restrict__ b3,
               const int* __restrict__ ids, const void* __restrict__ emb,
               const int* __restrict__ tree,
               unsigned short* __restrict__ WxT, unsigned short* __restrict__ WcatT,
               float* __restrict__ bcat, unsigned short* __restrict__ xb,
               float* __restrict__ h0,
               int* __restrict__ msk, int* __restrict__ rnk, int* __restrict__ cnt,
               const int* __restrict__ flags){
    int bid = blockIdx.x, tid = threadIdx.x;
    int is64 = flags[17];
    if (bid < 8){
        int st = bid;
        for (int c = tid; c < R_; c += 512){
            cnt[(0*NST + st)*R_ + c] = 0;
            cnt[(1*NST + st)*R_ + c] = 0;
            cnt[(2*NST + st)*R_ + c] = 0;
        }
        __syncthreads();
        __shared__ int wt[8];
        int runbase = 0;
        for (int ch = 0; ch < 2; ++ch){
            int t = ch*512 + tid;
            int b = t >> 7, s = t & 127;
            int base = (b*NST + st)*3*S_;
            int d0 = idx_read(tree, base + s, is64);
            int rd = (b<<7) + d0;
            int rr = (b<<7) + idx_read(tree, base + S_ + s, is64);
            int rl = (b<<7) + idx_read(tree, base + 2*S_ + s, is64);
            int m = (d0 != 0) ? 1 : 0;
            unsigned long long bal = __ballot(m);
            int lane = tid & 63, wv = tid >> 6;
            if (lane == 0) wt[wv] = __popcll(bal);
            __syncthreads();
            int bp = runbase, tot = 0;
            for (int w = 0; w < wv; ++w) bp += wt[w];
            for (int w = 0; w < 8; ++w) tot += wt[w];
            int rank = bp + __popcll(bal & ((1ull << lane) - 1ull));
            msk[st*R_ + t] = m;
            rnk[st*R_ + t] = m ? rank : 0;
            atomicAdd(&cnt[(0*NST + st)*R_ + rr], 1);
            atomicAdd(&cnt[(1*NST + st)*R_ + rl], 1);
            atomicAdd(&cnt[(2*NST + st)*R_ + rd], 1);
            runbase += tot;
            __syncthreads();
        }
    }
    int gt = bid*512 + tid;
    {   // WxT: 2048 n x 64 k-groups
        int f_wx = flags[1], f_wf = flags[6];
        for (int u = gt; u < 131072; u += GS2){
            int n = u >> 6, k0 = (u & 63)*8;
            unsigned short tmp[8];
            #pragma unroll
            for (int i = 0; i < 8; ++i){
                float v = (n < 1536) ? load_in(Wioux, (long long)(k0+i)*1536 + n, f_wx)
                                     : load_in(Wfx,   (long long)(k0+i)*512 + (n-1536), f_wf);
                tmp[i] = f2b(v);
            }
            *(v8s*)&WxT[(size_t)n*KD + k0] = *(v8s*)tmp;
        }
    }
    {   // WcatT
        int fWr=flags[2], fWl=flags[4], fW0=flags[7], fW1=flags[9], fW2=flags[11], fW3=flags[13];
        for (int u = gt; u < 131072; u += GS2){
            int n = u >> 6, k0 = (u & 63)*8;
            unsigned short tmp[8];
            #pragma unroll
            for (int i = 0; i < 8; ++i){
                long long k = k0 + i;
                float v;
                if      (n <  512) v = load_in(Wr, k*1536 + n, fWr);
                else if (n < 1024) v = load_in(Wl, k*1536 + (n-512), fWl);
                else if (n < 1536) { int c = n-1024; v = load_in(W0, k*512+c, fW0) + load_in(W1, k*512+c, fW1); }
                else               { int c = n-1536; v = load_in(W2, k*512+c, fW2) + load_in(W3, k*512+c, fW3); }
                tmp[i] = f2b(v);
            }
            *(v8s*)&WcatT[(size_t)n*KD + k0] = *(v8s*)tmp;
        }
    }
    {   // bcat
        int fbr=flags[3], fbl=flags[5], fb0=flags[8], fb1=flags[10], fb2=flags[12], fb3=flags[14];
        for (int n = gt; n < 2048; n += GS2){
            float v;
            if      (n <  512) v = load_in(br, n, fbr);
            else if (n < 1024) v = load_in(bl, n-512, fbl);
            else if (n < 1536) v = load_in(b0, n-1024, fb0) + load_in(b1, n-1024, fb1);
            else               v = load_in(b2, n-1536, fb2) + load_in(b3, n-1536, fb3);
            bcat[n] = v;
        }
    }
    {   // xb: 1024 rows x 64 groups
        int f_emb = flags[0], i64i = flags[16];
        for (int u = gt; u < 65536; u += GS2){
            int r = u >> 6, c0 = (u & 63)*8;
            long long base = (long long)idx_read(ids, r, i64i)*E_ + c0;
            unsigned short tmp[8];
            #pragma unroll
            for (int i = 0; i < 8; ++i) tmp[i] = f2b(load_in(emb, base + i, f_emb));
            *(v8s*)&xb[(size_t)r*KD + c0] = *(v8s*)tmp;
        }
    }
    for (int u = gt; u < 262144; u += GS2)   // zero h0+c0 (contiguous 4 MB)
        ((float4*)h0)[u] = make_float4(0.f,0.f,0.f,0.f);
}

// ---- K3: CSR scans ----
__global__ void csr_scan(const int* __restrict__ cnt, int* __restrict__ off,
                         int* __restrict__ cur){
    int st = blockIdx.x, a = blockIdx.y;
    int t = threadIdx.x;   // 1024
    int base = (a*NST + st)*R_;
    __shared__ int sh[R_];
    int v = cnt[base + t];
    sh[t] = v;
    __syncthreads();
    for (int d = 1; d < R_; d <<= 1){
        int x = (t >= d) ? sh[t - d] : 0;
        __syncthreads();
        sh[t] += x;
        __syncthreads();
    }
    int excl = sh[t] - v;
    off[base + t] = excl;
    cur[base + t] = excl;
}

// ---- K4: CSR fill ----
__global__ __launch_bounds__(512)
void csr_fill(const int* __restrict__ tree, int* __restrict__ cur,
              int* __restrict__ ent, const int* __restrict__ flags){
    int is64 = flags[17];
    int st = blockIdx.x;
    for (int ch = 0; ch < 2; ++ch){
        int t = ch*512 + threadIdx.x;
        int b = t >> 7, s = t & 127;
        int base = (b*NST + st)*3*S_;
        int rd = (b<<7) + idx_read(tree, base + s, is64);
        int rr = (b<<7) + idx_read(tree, base + S_ + s, is64);
        int rl = (b<<7) + idx_read(tree, base + 2*S_ + s, is64);
        int p0 = atomicAdd(&cur[(0*NST + st)*R_ + rr], 1);
        ent[(0*NST + st)*R_ + p0] = t;
        int p1 = atomicAdd(&cur[(1*NST + st)*R_ + rl], 1);
        ent[(1*NST + st)*R_ + p1] = t;
        int p2 = atomicAdd(&cur[(2*NST + st)*R_ + rd], 1);
        ent[(2*NST + st)*R_ + p2] = t | (rr << 10) | (rl << 20);
    }
}

// ---- MFMA GEMM (r7-proven): C[1024][2048] = A@BT^T (+bias) ----
// 64x64 tile, 512 blocks (2/CU), 4 waves 2x2 of 32x32, register-prefetched staging.
__global__ __launch_bounds__(256)
void gemm_bf16(const unsigned short* __restrict__ A,
               const unsigned short* __restrict__ BT,
               const float* __restrict__ bias,
               float* __restrict__ C){
    __shared__ short As[64*LDA];
    __shared__ short Bs[64*LDA];
    int bn = blockIdx.x, bm = blockIdx.y;
    int tid = threadIdx.x;
    int lane = tid & 63, wave = tid >> 6;
    int wm = wave & 1, wn = wave >> 1;
    int lm = lane & 15, quad = lane >> 4;
    v4f acc[2][2];
    #pragma unroll
    for (int i=0;i<2;++i)
        #pragma unroll
        for (int j=0;j<2;++j) acc[i][j] = (v4f)0.0f;

    int srow = tid >> 3, sg = (tid & 7)*8;
    const unsigned short* Ab = A  + (size_t)(bm*64)*KD;
    const unsigned short* Bb = BT + (size_t)(bn*64)*KD;
    v8s pa[2], pb[2];
    #pragma unroll
    for (int j=0;j<2;++j){
        pa[j] = *(const v8s*)(Ab + (size_t)(j*32+srow)*KD + sg);
        pb[j] = *(const v8s*)(Bb + (size_t)(j*32+srow)*KD + sg);
    }
    for (int k0 = 0; k0 < KD; k0 += 64){
        #pragma unroll
        for (int j=0;j<2;++j){
            *(v8s*)&As[(j*32+srow)*LDA + sg] = pa[j];
            *(v8s*)&Bs[(j*32+srow)*LDA + sg] = pb[j];
        }
        __syncthreads();
        int k1 = k0 + 64;
        if (k1 < KD){
            #pragma unroll
            for (int j=0;j<2;++j){
                pa[j] = *(const v8s*)(Ab + (size_t)(j*32+srow)*KD + k1 + sg);
                pb[j] = *(const v8s*)(Bb + (size_t)(j*32+srow)*KD + k1 + sg);
            }
        }
        #pragma unroll
        for (int kk = 0; kk < 64; kk += 32){
            v8s af[2], bf[2];
            #pragma unroll
            for (int i=0;i<2;++i){
                af[i] = *(const v8s*)&As[(wm*32 + i*16 + lm)*LDA + kk + quad*8];
                bf[i] = *(const v8s*)&Bs[(wn*32 + i*16 + lm)*LDA + kk + quad*8];
            }
            #pragma unroll
            for (int i=0;i<2;++i)
                #pragma unroll
                for (int j=0;j<2;++j)
                    acc[i][j] = __builtin_amdgcn_mfma_f32_16x16x32_bf16(af[i], bf[j], acc[i][j], 0, 0, 0);
        }
        __syncthreads();
    }
    #pragma unroll
    for (int j=0;j<2;++j){
        int n = bn*64 + wn*32 + j*16 + lm;
        float bv = bias ? bias[n] : 0.0f;
        #pragma unroll
        for (int i=0;i<2;++i){
            int m0 = bm*64 + wm*32 + i*16 + quad*4;
            #pragma unroll
            for (int rg = 0; rg < 4; ++rg)
                C[(size_t)(m0+rg)*N2 + n] = acc[i][j][rg] + bv;
        }
    }
}

// ---- per-step epilogue: CSR-gathered scatters + gates + masked-scatter ----
// tstr=0 with T=bcat implements the step-0 (h=0 => T = bias broadcast) shortcut.
__global__ __launch_bounds__(512)
void step_epi(const float* __restrict__ XO, const float* __restrict__ T, int tstr,
              const float* __restrict__ hc, const float* __restrict__ cc,
              float* __restrict__ hn, float* __restrict__ cn,
              unsigned short* __restrict__ hb, float* __restrict__ out,
              const int* __restrict__ msk, const int* __restrict__ rnk,
              const int* __restrict__ cnt, const int* __restrict__ off,
              const int* __restrict__ ent, int st, int last){
    int r = blockIdx.x, c = threadIdx.x;      // 1024 blocks x 512 threads
    if (!msk[st*R_ + r]){
        float hv = hc[(size_t)r*H_ + c];
        if (last){ out[(size_t)r*H_ + c] = hv; return; }
        hn[(size_t)r*H_ + c] = hv;
        cn[(size_t)r*H_ + c] = cc[(size_t)r*H_ + c];
        hb[(size_t)r*KD + c] = f2b(hv);
        return;
    }
    int j = rnk[st*R_ + r];
    int bR = off[(0*NST+st)*R_ + j], dR = cnt[(0*NST+st)*R_ + j];
    int bL = off[(1*NST+st)*R_ + j], dL = cnt[(1*NST+st)*R_ + j];
    int bD = off[(2*NST+st)*R_ + j], dD = cnt[(2*NST+st)*R_ + j];
    const int* eR = ent + (0*NST+st)*R_ + bR;
    const int* eL = ent + (1*NST+st)*R_ + bL;
    const int* eD = ent + (2*NST+st)*R_ + bD;
    const float* xo = XO + (size_t)j*N2;
    float scv = 0.f;
    for (int e = 0; e < dR; ++e) scv += T[(size_t)eR[e]*tstr + c];
    for (int e = 0; e < dL; ++e) scv += T[(size_t)eL[e]*tstr + 512 + c];
    float fxv = xo[1536 + c];
    float csc = 0.f;
    for (int e = 0; e < dD; ++e){
        int pk = eD[e];
        int s  = pk & 1023, rr = (pk >> 10) & 1023, rl = (pk >> 20) & 1023;
        float f = sigm(fxv + T[(size_t)rr*tstr + 1024 + c] + T[(size_t)rl*tstr + 1536 + c]);
        csc += f * cc[(size_t)s*H_ + c];
    }
    float ig = sigm(xo[c] + scv);
    float og = sigm(xo[512 + c]);
    float ug = tanhf(xo[1024 + c]);
    float cf = ig*ug + csc;
    float hf = og * tanhf(cf);
    if (last){ out[(size_t)r*H_ + c] = hf; return; }
    hn[(size_t)r*H_ + c] = hf;
    cn[(size_t)r*H_ + c] = cf;
    hb[(size_t)r*KD + c] = f2b(hf);
}

extern "C" void kernel_launch(void* const* d_in, const int* in_sizes, int n_in,
                              void* d_out, int out_size, void* d_ws, size_t ws_size,
                              hipStream_t stream) {
    const int* input_ids = (const int*)d_in[0];
    const int* tree      = (const int*)d_in[1];

    char* wp = (char*)d_ws;
    auto alloc = [&](size_t bytes) -> void* {
        void* q = (void*)wp;
        wp += (bytes + 255) & ~(size_t)255;
        return q;
    };
    float*          XO     = (float*)alloc((size_t)R_*N2*4);
    float*          T      = (float*)alloc((size_t)R_*N2*4);
    float*          h0     = (float*)alloc((size_t)R_*H_*4);   // contiguous with c0
    float*          c0     = (float*)alloc((size_t)R_*H_*4);
    float*          h1     = (float*)alloc((size_t)R_*H_*4);
    float*          c1     = (float*)alloc((size_t)R_*H_*4);
    unsigned short* WxT    = (unsigned short*)alloc((size_t)N2*KD*2);
    unsigned short* WcatT  = (unsigned short*)alloc((size_t)N2*KD*2);
    float*          bcat   = (float*)alloc((size_t)N2*4);
    unsigned short* xb     = (unsigned short*)alloc((size_t)R_*KD*2);
    unsigned short* hb     = (unsigned short*)alloc((size_t)R_*KD*2);
    int*            msk    = (int*)alloc((size_t)NST*R_*4);
    int*            rnk    = (int*)alloc((size_t)NST*R_*4);
    int*            cnt    = (int*)alloc((size_t)3*NST*R_*4);
    int*            off    = (int*)alloc((size_t)3*NST*R_*4);
    int*            cur    = (int*)alloc((size_t)3*NST*R_*4);
    int*            ent    = (int*)alloc((size_t)3*NST*R_*4);
    int*            flags  = (int*)alloc(256);
    float*          out    = (float*)d_out;   // fp32 output (verified r4)

    hipLaunchKernelGGL(probe_all, dim3(17), dim3(1024), 0, stream,
                       d_in[2], d_in[3], d_in[4], d_in[5], d_in[6], d_in[7], d_in[8],
                       d_in[9], d_in[10], d_in[11], d_in[12], d_in[13], d_in[14],
                       d_in[15], d_in[16], input_ids, tree, flags);
    hipLaunchKernelGGL(rank_pack, dim3(NB2), dim3(512), 0, stream,
                       d_in[3], d_in[8],
                       d_in[4], d_in[6], d_in[9], d_in[11], d_in[13], d_in[15],
                       d_in[5], d_in[7], d_in[10], d_in[12], d_in[14], d_in[16],
                       input_ids, d_in[2], tree,
                       WxT, WcatT, bcat, xb, h0, msk, rnk, cnt, flags);
    hipLaunchKernelGGL(csr_scan, dim3(NST, 3), dim3(1024), 0, stream, cnt, off, cur);
    hipLaunchKernelGGL(csr_fill, dim3(NST), dim3(512), 0, stream, tree, cur, ent, flags);

    // XO = xb @ WxT^T  (1024 x 2048, K=512), no bias
    hipLaunchKernelGGL(gemm_bf16, dim3(N2/64, R_/64), dim3(256), 0, stream,
                       xb, WxT, (const float*)nullptr, XO);

    float *hc = h0, *cc = c0, *hn = h1, *cn = c1;
    // step 0: h==0 -> T is the bias broadcast; no GEMM needed (tstr=0, T=bcat)
    hipLaunchKernelGGL(step_epi, dim3(R_), dim3(512), 0, stream,
                       XO, bcat, 0, hc, cc, hn, cn, hb, out,
                       msk, rnk, cnt, off, ent, 0, 0);
    { float* t1 = hc; hc = hn; hn = t1; float* t2 = cc; cc = cn; cn = t2; }

    for (int st = 1; st < NST; ++st){
        hipLaunchKernelGGL(gemm_bf16, dim3(N2/64, R_/64), dim3(256), 0, stream,
                           hb, WcatT, bcat, T);
        hipLaunchKernelGGL(step_epi, dim3(R_), dim3(512), 0, stream,
                           XO, T, N2, hc, cc, hn, cn, hb, out,
                           msk, rnk, cnt, off, ent, st, (st == NST-1) ? 1 : 0);
        float* t1 = hc; hc = hn; hn = t1;
        float* t2 = cc; cc = cn; cn = t2;
    }
}